// Round 10
// baseline (431.967 us; speedup 1.0000x reference)
//
#include <hip/hip_runtime.h>

typedef unsigned short u16;
typedef unsigned int u32;
typedef unsigned char u8;
typedef unsigned long long u64;

#define GG   512
#define NPG  90
#define NTOT (GG*NPG)
#define NED  921600
#define FIN  90
#define HC   64
#define KP   70
#define CAPB 2176   // bucket capacity: mean 1800 + 8.9 sigma

#define SAD  91   // x/A f32 stride: 27l mod 32 bijective -> conflict-free
#define SP   68   // P stride (float4 writes; Agg reads are full-wave broadcast)
#define SR   67   // r1/h2 scalar stride: 3l mod 32 bijective -> conflict-free

// wf (f32 weights in ws) layout, float offsets:
#define WF_W1L 0
#define WF_W1R 5760
#define WF_W2L 11520
#define WF_W2R 15616
#define WF_B1  19712
#define WF_B2  19776
#define WF_FOLD 19840
#define WF_ZC  24320
#define WF_FLAG 24321

__device__ __forceinline__ float bf2f(u16 u) {
    union { u32 i; float f; } v; v.i = ((u32)u) << 16; return v.f;
}
__device__ __forceinline__ float bflo(u32 u) {
    union { u32 i; float f; } v; v.i = u << 16; return v.f;
}
__device__ __forceinline__ float bfhi(u32 u) {
    union { u32 i; float f; } v; v.i = u & 0xFFFF0000u; return v.f;
}
__device__ __forceinline__ u16 f2bf(float f) {
    union { float f; u32 i; } v; v.f = f;
    u32 r = (v.i + 0x7FFFu + ((v.i >> 16) & 1u)) >> 16;
    return (u16)r;
}
__device__ __forceinline__ float ldadp(const void* p, long long i, int isf32) {
    return isf32 ? ((const float*)p)[i] : bf2f(((const u16*)p)[i]);
}

// ---- merged prep: edge->bucket scatter + weight convert + MLP fold.
__global__ __launch_bounds__(256) void k_pre(
    const u32* __restrict__ xw, const int* __restrict__ ei,
    const void* W1l, const void* W1r, const void* b1,
    const void* W2l, const void* W2r, const void* b2,
    const void* Wl1, const void* bl1, const void* Wl2, const void* bl2,
    int* __restrict__ cnt, u16* __restrict__ bucket, float* __restrict__ wf)
{
    __shared__ int sf;
    const int t = threadIdx.x;
    const int b = blockIdx.x;

    if (b < 900) {
        int lane = t & 63;
        u32 v = (lane < 16) ? (u32)ei[lane] : 0u;
        u64 bb = __ballot((lane & 1) && (v != 0));
        bool wide = (bb == 0ull);          // int64: odd (hi) words all zero
        int e0 = b * 1024 + t * 4;
        int s[4], d[4];
        if (wide) {
            uint4 s01 = *(const uint4*)(ei + 2 * e0);
            uint4 s23 = *(const uint4*)(ei + 2 * e0 + 4);
            uint4 d01 = *(const uint4*)(ei + 2 * (NED + e0));
            uint4 d23 = *(const uint4*)(ei + 2 * (NED + e0) + 4);
            s[0] = (int)s01.x; s[1] = (int)s01.z; s[2] = (int)s23.x; s[3] = (int)s23.z;
            d[0] = (int)d01.x; d[1] = (int)d01.z; d[2] = (int)d23.x; d[3] = (int)d23.z;
        } else {
            uint4 ss = *(const uint4*)(ei + e0);
            uint4 dd = *(const uint4*)(ei + NED + e0);
            s[0] = (int)ss.x; s[1] = (int)ss.y; s[2] = (int)ss.z; s[3] = (int)ss.w;
            d[0] = (int)dd.x; d[1] = (int)dd.y; d[2] = (int)dd.z; d[3] = (int)dd.w;
        }
        #pragma unroll
        for (int k = 0; k < 4; ++k) {
            int dk = d[k];
            if ((unsigned)dk >= NTOT) continue;
            int g = (unsigned)dk / NPG;
            int dl = dk - g * NPG;
            int ls = s[k] - g * NPG;
            if ((unsigned)ls >= NPG) continue;
            int pos = atomicAdd(&cnt[g], 1);
            if (pos < CAPB)
                bucket[(size_t)g * CAPB + pos] = (u16)((dl << 7) | ls);
        }
        return;
    }

    if (t < 64) {
        u32 e = (xw[t] >> 7) & 0xFF;       // exponent of low-half-as-bf16
        u64 bb = __ballot(e >= 136);       // impossible for N(0,1)-scale bf16
        if (t == 0) sf = (bb != 0ull) ? 1 : 0;
    }
    __syncthreads();
    const int f32 = sf;

    if (b < 978) {
        int i = (b - 900) * 256 + t;
        if      (i < 5760)  wf[i] = ldadp(W1l, i, f32);
        else if (i < 11520) wf[i] = ldadp(W1r, i - 5760, f32);
        else if (i < 15616) wf[i] = ldadp(W2l, i - 11520, f32);
        else if (i < 19712) wf[i] = ldadp(W2r, i - 15616, f32);
        else if (i < 19776) wf[i] = ldadp(b1, i - 19712, f32);
        else if (i < 19840) wf[i] = ldadp(b2, i - 19776, f32);
        if (b == 900 && t == 0) wf[WF_FLAG] = f32 ? 1.0f : 0.0f;
    } else {
        int m = (b - 978) * 256 + t;
        if (m < 4480) {
            float s = 0.f;
            for (int j = 0; j < HC; ++j)
                s += ldadp(Wl1, (long long)m * HC + j, f32) * ldadp(Wl2, j, f32);
            wf[WF_FOLD + m] = s;
        } else if (m == 4480) {
            float s = ldadp(bl2, 0, f32);
            for (int j = 0; j < HC; ++j)
                s += ldadp(bl1, j, f32) * ldadp(Wl2, j, f32);
            wf[WF_ZC] = s;
        }
    }
}

// ---- fused pipeline: 8 waves x 8-col slab (wave-uniform), lane = rows l, l+64
__global__ __launch_bounds__(512, 4) void k_fused(
    const void* __restrict__ x, const int* __restrict__ cnt,
    const u16* __restrict__ bucket, const float* __restrict__ wf,
    void* __restrict__ dout)
{
    __shared__ __align__(16) char smem[58144];
    float* As    = (float*)smem;                 // [90][91] f32: x, then A (LDS-built)
    float* R1    = (float*)(smem + 32768);       // P/r1/P2/h2
    float* s_key = (float*)(smem + 57248);       // [90]
    int*   s_deg = (int*)(smem + 57608);         // [90]
    float* s_red = (float*)(smem + 57968);       // [8]
    u16*   s_ord = (u16*)(smem + 58000);         // [72]

    const int g = blockIdx.x;
    const int t = threadIdx.x;
    const bool isf32 = (wf[WF_FLAG] > 0.5f);

    const int l = t & 63;
    const int w = __builtin_amdgcn_readfirstlane(t >> 6);  // wave id, SGPR
    const int jb = w * 8;                                   // wave-uniform slab
    const int row0 = l;
    const bool has2 = (l < NPG - 64);
    const int row1 = has2 ? l + 64 : l;

    // ---- prefetch this graph's edge bucket into registers (hidden under GEMM1) ----
    const int cnt_g = min(cnt[g], CAPB);
    int ebuf[5];
    #pragma unroll
    for (int j = 0; j < 5; ++j) {
        int idx = t + j * 512;
        ebuf[j] = (idx < cnt_g) ? (int)bucket[(size_t)g * CAPB + idx] : -1;
    }

    // ---- stage x -> As (expand bf16 to f32; single GEMM path) ----
    if (isf32) {
        const float* xg = (const float*)x + (size_t)g * 8100;
        for (int p = t; p < 8100; p += 512) {
            int r = p / NPG, c = p - r * NPG;
            As[r * SAD + c] = xg[p];
        }
    } else {
        const u32* xg = (const u32*)((const u16*)x + (size_t)g * 8100);
        for (int p = t; p < 4050; p += 512) {
            int r = p / 45, c = (p - r * 45) * 2;
            u32 v = xg[p];
            As[r * SAD + c]     = bflo(v);
            As[r * SAD + c + 1] = bfhi(v);
        }
    }
    __syncthreads();  // B0

    // ---- GEMM1: P = x@W1l, Q = x@W1r + b1 (regs); weights scalar-uniform ----
    float accP[2][8], accQ[2][8];
    {
        const float* bb = wf + WF_B1 + jb;
        #pragma unroll
        for (int j = 0; j < 8; ++j) {
            float bv = bb[j];
            accP[0][j] = 0.f; accP[1][j] = 0.f;
            accQ[0][j] = bv;  accQ[1][j] = bv;
        }
    }
    {
        const float* WL = wf + WF_W1L + jb;
        const float* WR = wf + WF_W1R + jb;
        #pragma unroll 3
        for (int k = 0; k < FIN; ++k) {
            float wl[8], wr[8];
            #pragma unroll
            for (int j = 0; j < 8; ++j) { wl[j] = WL[k * HC + j]; wr[j] = WR[k * HC + j]; }
            float x0 = As[row0 * SAD + k];
            float x1 = As[row1 * SAD + k];
            #pragma unroll
            for (int j = 0; j < 8; ++j) {
                accP[0][j] += x0 * wl[j]; accQ[0][j] += x0 * wr[j];
                accP[1][j] += x1 * wl[j]; accQ[1][j] += x1 * wr[j];
            }
        }
    }
    __syncthreads();  // B1: x reads done, As reusable for A

    // ---- write P to R1; zero A + deg ----
    *(float4*)(R1 + row0 * SP + jb)     = make_float4(accP[0][0], accP[0][1], accP[0][2], accP[0][3]);
    *(float4*)(R1 + row0 * SP + jb + 4) = make_float4(accP[0][4], accP[0][5], accP[0][6], accP[0][7]);
    if (has2) {
        *(float4*)(R1 + row1 * SP + jb)     = make_float4(accP[1][0], accP[1][1], accP[1][2], accP[1][3]);
        *(float4*)(R1 + row1 * SP + jb + 4) = make_float4(accP[1][4], accP[1][5], accP[1][6], accP[1][7]);
    }
    {
        float4 z4 = make_float4(0.f, 0.f, 0.f, 0.f);
        #pragma unroll
        for (int j = 0; j < 4; ++j) ((float4*)As)[t + j * 512] = z4;
        if (t < NPG) s_deg[t] = 0;
    }
    __syncthreads();  // B1b: zeroing complete

    // ---- build A in LDS from bucket ----
    #pragma unroll
    for (int j = 0; j < 5; ++j) {
        int e = ebuf[j];
        if (e >= 0) {
            int dl = e >> 7, ls = e & 127;
            atomicAdd(&As[dl * SAD + ls], 1.0f);
            atomicAdd(&s_deg[dl], 1);
        }
    }
    __syncthreads();  // B2: A complete

    const float rc0 = 1.0f / (float)max(s_deg[row0], 1);
    const float rc1 = 1.0f / (float)max(s_deg[row1], 1);

    // ---- Agg1: h1 = rc*(A@P) + Q ; x_train out; r1 -> regs ----
    float r1v[2][8];
    {
        float acc[2][8];
        #pragma unroll
        for (int i = 0; i < 2; ++i)
            #pragma unroll
            for (int j = 0; j < 8; ++j) acc[i][j] = 0.f;
        for (int k = 0; k < NPG; ++k) {
            float4 p0 = *(const float4*)(R1 + k * SP + jb);     // full-wave broadcast
            float4 p1 = *(const float4*)(R1 + k * SP + jb + 4);
            float pv[8] = {p0.x,p0.y,p0.z,p0.w,p1.x,p1.y,p1.z,p1.w};
            float a0 = As[row0 * SAD + k];
            float a1 = As[row1 * SAD + k];
            #pragma unroll
            for (int j = 0; j < 8; ++j) {
                acc[0][j] += a0 * pv[j];
                acc[1][j] += a1 * pv[j];
            }
        }
        #pragma unroll
        for (int i = 0; i < 2; ++i) {
            if (i == 0 || has2) {
                int n = i ? row1 : row0;
                float rc = i ? rc1 : rc0;
                float h[8];
                #pragma unroll
                for (int j = 0; j < 8; ++j) h[j] = fmaf(rc, acc[i][j], accQ[i][j]);
                size_t base = 512 + (size_t)(g * NPG + n) * HC + jb;
                if (isf32) {
                    *(float4*)((float*)dout + base)     = make_float4(h[0],h[1],h[2],h[3]);
                    *(float4*)((float*)dout + base + 4) = make_float4(h[4],h[5],h[6],h[7]);
                } else {
                    uint4 pk;
                    pk.x = (u32)f2bf(h[0]) | ((u32)f2bf(h[1]) << 16);
                    pk.y = (u32)f2bf(h[2]) | ((u32)f2bf(h[3]) << 16);
                    pk.z = (u32)f2bf(h[4]) | ((u32)f2bf(h[5]) << 16);
                    pk.w = (u32)f2bf(h[6]) | ((u32)f2bf(h[7]) << 16);
                    *(uint4*)((u16*)dout + base) = pk;
                }
                #pragma unroll
                for (int j = 0; j < 8; ++j) r1v[i][j] = fmaxf(h[j], 0.f);
            }
        }
    }
    __syncthreads();  // B3: P reads done
    #pragma unroll
    for (int j = 0; j < 8; ++j) R1[row0 * SR + jb + j] = r1v[0][j];
    if (has2) {
        #pragma unroll
        for (int j = 0; j < 8; ++j) R1[row1 * SR + jb + j] = r1v[1][j];
    }
    __syncthreads();  // B4

    // ---- GEMM2: P2 = r1@W2l, Q2 = r1@W2r + b2 (regs) ----
    {
        const float* bb = wf + WF_B2 + jb;
        #pragma unroll
        for (int j = 0; j < 8; ++j) {
            float bv = bb[j];
            accP[0][j] = 0.f; accP[1][j] = 0.f;
            accQ[0][j] = bv;  accQ[1][j] = bv;
        }
    }
    {
        const float* WL = wf + WF_W2L + jb;
        const float* WR = wf + WF_W2R + jb;
        #pragma unroll 4
        for (int k = 0; k < HC; ++k) {
            float wl[8], wr[8];
            #pragma unroll
            for (int j = 0; j < 8; ++j) { wl[j] = WL[k * HC + j]; wr[j] = WR[k * HC + j]; }
            float v0 = R1[row0 * SR + k];
            float v1 = R1[row1 * SR + k];
            #pragma unroll
            for (int j = 0; j < 8; ++j) {
                accP[0][j] += v0 * wl[j]; accQ[0][j] += v0 * wr[j];
                accP[1][j] += v1 * wl[j]; accQ[1][j] += v1 * wr[j];
            }
        }
    }
    __syncthreads();  // B5: r1 reads done
    *(float4*)(R1 + row0 * SP + jb)     = make_float4(accP[0][0], accP[0][1], accP[0][2], accP[0][3]);
    *(float4*)(R1 + row0 * SP + jb + 4) = make_float4(accP[0][4], accP[0][5], accP[0][6], accP[0][7]);
    if (has2) {
        *(float4*)(R1 + row1 * SP + jb)     = make_float4(accP[1][0], accP[1][1], accP[1][2], accP[1][3]);
        *(float4*)(R1 + row1 * SP + jb + 4) = make_float4(accP[1][4], accP[1][5], accP[1][6], accP[1][7]);
    }
    __syncthreads();  // B6

    // ---- Agg2: h2 = rc*(A@P2) + Q2 ; key = col 63 ----
    float h2v[2][8];
    {
        float acc[2][8];
        #pragma unroll
        for (int i = 0; i < 2; ++i)
            #pragma unroll
            for (int j = 0; j < 8; ++j) acc[i][j] = 0.f;
        for (int k = 0; k < NPG; ++k) {
            float4 p0 = *(const float4*)(R1 + k * SP + jb);
            float4 p1 = *(const float4*)(R1 + k * SP + jb + 4);
            float pv[8] = {p0.x,p0.y,p0.z,p0.w,p1.x,p1.y,p1.z,p1.w};
            float a0 = As[row0 * SAD + k];
            float a1 = As[row1 * SAD + k];
            #pragma unroll
            for (int j = 0; j < 8; ++j) {
                acc[0][j] += a0 * pv[j];
                acc[1][j] += a1 * pv[j];
            }
        }
        #pragma unroll
        for (int i = 0; i < 2; ++i) {
            if (i == 0 || has2) {
                int n = i ? row1 : row0;
                float rc = i ? rc1 : rc0;
                #pragma unroll
                for (int j = 0; j < 8; ++j)
                    h2v[i][j] = fmaf(rc, acc[i][j], accQ[i][j]);
                if (w == 7) s_key[n] = h2v[i][7];
            }
        }
    }
    __syncthreads();  // B7: P2 reads done; s_key complete
    #pragma unroll
    for (int j = 0; j < 8; ++j) R1[row0 * SR + jb + j] = h2v[0][j];
    if (has2) {
        #pragma unroll
        for (int j = 0; j < 8; ++j) R1[row1 * SR + jb + j] = h2v[1][j];
    }
    // stable descending rank (== stable argsort(-key))
    if (t < NPG) {
        float my = s_key[t];
        int r = 0;
        for (int m2 = 0; m2 < NPG; ++m2) {
            float km = s_key[m2];
            r += (km > my) || (km == my && m2 < t);
        }
        if (r < KP) s_ord[r] = (u16)t;
    }
    __syncthreads();  // B8

    // ---- folded MLP: z = sum p*W_fold + zc ; sigmoid ----
    float zp = 0.f;
    for (int p = t; p < KP * HC; p += 512) {
        int i = p >> 6, c = p & 63;
        int nn = s_ord[i];
        zp += R1[nn * SR + c] * wf[WF_FOLD + p];
    }
    #pragma unroll
    for (int off = 32; off > 0; off >>= 1) zp += __shfl_down(zp, off);
    if ((t & 63) == 0) s_red[t >> 6] = zp;
    __syncthreads();  // B9
    if (t == 0) {
        float z = wf[WF_ZC];
        #pragma unroll
        for (int i = 0; i < 8; ++i) z += s_red[i];
        float sg = 1.0f / (1.0f + expf(-z));
        if (isf32) ((float*)dout)[g] = sg;
        else       ((u16*)dout)[g]   = f2bf(sg);
    }
}

extern "C" void kernel_launch(void* const* d_in, const int* in_sizes, int n_in,
                              void* d_out, int out_size, void* d_ws, size_t ws_size,
                              hipStream_t stream) {
    const void* x   = d_in[0];
    const int*  ei  = (const int*)d_in[1];
    const void* W1l = d_in[3];
    const void* W1r = d_in[4];
    const void* b1  = d_in[5];
    const void* W2l = d_in[6];
    const void* W2r = d_in[7];
    const void* b2  = d_in[8];
    const void* Wl1 = d_in[9];
    const void* bl1 = d_in[10];
    const void* Wl2 = d_in[11];
    const void* bl2 = d_in[12];

    char* ws     = (char*)d_ws;
    int*   cnt   = (int*)ws;                     // 2,048 B (512 cursors)
    u16*   bucket= (u16*)(ws + 2048);            // 2,228,224 B (512 x 2176 u16)
    float* wf    = (float*)(ws + 2230272);       // 97,288 B (total ~2.33 MB)

    hipMemsetAsync(cnt, 0, 2048, stream);
    k_pre<<<996, 256, 0, stream>>>((const u32*)x, ei, W1l, W1r, b1, W2l, W2r, b2,
                                   Wl1, bl1, Wl2, bl2, cnt, bucket, wf);
    k_fused<<<GG, 512, 0, stream>>>(x, cnt, bucket, wf, d_out);
}

// Round 11
// 183.108 us; speedup vs baseline: 2.3591x; 2.3591x over previous
//
#include <hip/hip_runtime.h>

typedef unsigned short u16;
typedef unsigned int u32;
typedef unsigned char u8;
typedef unsigned long long u64;

#define GG   512
#define NPG  90
#define NTOT (GG*NPG)
#define NED  921600
#define FIN  90
#define HC   64
#define KP   70
#define AW   23      // packed-A words per row (23*4 = 92 >= 90)
#define AWG  (NPG*AW) // 2070 words per graph

#define SAD  91   // x/A f32 stride: 27l mod 32 bijective -> conflict-free
#define SP   68   // P stride (float4 writes; Agg reads are full-wave broadcast)
#define SR   67   // r1/h2 scalar stride: 3l mod 32 bijective -> conflict-free

// wf (f32 weights in ws) layout, float offsets:
#define WF_W1L 0
#define WF_W1R 5760
#define WF_W2L 11520
#define WF_W2R 15616
#define WF_B1  19712
#define WF_B2  19776
#define WF_FOLD 19840
#define WF_ZC  24320
#define WF_FLAG 24321

__device__ __forceinline__ float bf2f(u16 u) {
    union { u32 i; float f; } v; v.i = ((u32)u) << 16; return v.f;
}
__device__ __forceinline__ float bflo(u32 u) {
    union { u32 i; float f; } v; v.i = u << 16; return v.f;
}
__device__ __forceinline__ float bfhi(u32 u) {
    union { u32 i; float f; } v; v.i = u & 0xFFFF0000u; return v.f;
}
__device__ __forceinline__ u16 f2bf(float f) {
    union { float f; u32 i; } v; v.f = f;
    u32 r = (v.i + 0x7FFFu + ((v.i >> 16) & 1u)) >> 16;
    return (u16)r;
}
__device__ __forceinline__ float ldadp(const void* p, long long i, int isf32) {
    return isf32 ? ((const float*)p)[i] : bf2f(((const u16*)p)[i]);
}

// ---- merged prep: byte-packed dense-A build + weight convert + MLP fold.
__global__ __launch_bounds__(256) void k_pre(
    const u32* __restrict__ xw, const int* __restrict__ ei,
    const void* W1l, const void* W1r, const void* b1,
    const void* W2l, const void* W2r, const void* b2,
    const void* Wl1, const void* bl1, const void* Wl2, const void* bl2,
    u32* __restrict__ A32, float* __restrict__ wf)
{
    __shared__ int sf;
    const int t = threadIdx.x;
    const int b = blockIdx.x;

    if (b < 900) {
        int lane = t & 63;
        u32 v = (lane < 16) ? (u32)ei[lane] : 0u;
        u64 bb = __ballot((lane & 1) && (v != 0));
        bool wide = (bb == 0ull);          // int64: odd (hi) words all zero
        int e0 = b * 1024 + t * 4;
        int s[4], d[4];
        if (wide) {
            uint4 s01 = *(const uint4*)(ei + 2 * e0);
            uint4 s23 = *(const uint4*)(ei + 2 * e0 + 4);
            uint4 d01 = *(const uint4*)(ei + 2 * (NED + e0));
            uint4 d23 = *(const uint4*)(ei + 2 * (NED + e0) + 4);
            s[0] = (int)s01.x; s[1] = (int)s01.z; s[2] = (int)s23.x; s[3] = (int)s23.z;
            d[0] = (int)d01.x; d[1] = (int)d01.z; d[2] = (int)d23.x; d[3] = (int)d23.z;
        } else {
            uint4 ss = *(const uint4*)(ei + e0);
            uint4 dd = *(const uint4*)(ei + NED + e0);
            s[0] = (int)ss.x; s[1] = (int)ss.y; s[2] = (int)ss.z; s[3] = (int)ss.w;
            d[0] = (int)dd.x; d[1] = (int)dd.y; d[2] = (int)dd.z; d[3] = (int)dd.w;
        }
        #pragma unroll
        for (int k = 0; k < 4; ++k) {
            int dk = d[k];
            if ((unsigned)dk >= NTOT) continue;
            int g = (unsigned)dk / NPG;
            int dl = dk - g * NPG;
            int ls = s[k] - g * NPG;
            if ((unsigned)ls >= NPG) continue;
            atomicAdd(&A32[(size_t)g * AWG + dl * AW + (ls >> 2)],
                      1u << (8 * (ls & 3)));
        }
        return;
    }

    if (t < 64) {
        u32 e = (xw[t] >> 7) & 0xFF;       // exponent of low-half-as-bf16
        u64 bb = __ballot(e >= 136);       // impossible for N(0,1)-scale bf16
        if (t == 0) sf = (bb != 0ull) ? 1 : 0;
    }
    __syncthreads();
    const int f32 = sf;

    if (b < 978) {
        int i = (b - 900) * 256 + t;
        if      (i < 5760)  wf[i] = ldadp(W1l, i, f32);
        else if (i < 11520) wf[i] = ldadp(W1r, i - 5760, f32);
        else if (i < 15616) wf[i] = ldadp(W2l, i - 11520, f32);
        else if (i < 19712) wf[i] = ldadp(W2r, i - 15616, f32);
        else if (i < 19776) wf[i] = ldadp(b1, i - 19712, f32);
        else if (i < 19840) wf[i] = ldadp(b2, i - 19776, f32);
        if (b == 900 && t == 0) wf[WF_FLAG] = f32 ? 1.0f : 0.0f;
    } else {
        int m = (b - 978) * 256 + t;
        if (m < 4480) {
            float s = 0.f;
            for (int j = 0; j < HC; ++j)
                s += ldadp(Wl1, (long long)m * HC + j, f32) * ldadp(Wl2, j, f32);
            wf[WF_FOLD + m] = s;
        } else if (m == 4480) {
            float s = ldadp(bl2, 0, f32);
            for (int j = 0; j < HC; ++j)
                s += ldadp(bl1, j, f32) * ldadp(Wl2, j, f32);
            wf[WF_ZC] = s;
        }
    }
}

// ---- fused pipeline: 8 waves x 8-col slab (wave-uniform), lane = rows l, l+64
__global__ __launch_bounds__(512, 4) void k_fused(
    const void* __restrict__ x, const u32* __restrict__ A32,
    const float* __restrict__ wf, void* __restrict__ dout)
{
    __shared__ __align__(16) char smem[58144];
    float* As    = (float*)smem;                 // [90][91] f32: x, then A
    float* R1    = (float*)(smem + 32768);       // P/r1/P2/h2
    float* s_key = (float*)(smem + 57248);       // [90]
    float* s_red = (float*)(smem + 57968);       // [8]
    u16*   s_ord = (u16*)(smem + 58000);         // [72]

    const int g = blockIdx.x;
    const int t = threadIdx.x;
    const bool isf32 = (wf[WF_FLAG] > 0.5f);

    const int l = t & 63;
    const int w = __builtin_amdgcn_readfirstlane(t >> 6);  // wave id, SGPR
    const int jb = w * 8;                                   // wave-uniform slab
    const int row0 = l;
    const bool has2 = (l < NPG - 64);
    const int row1 = has2 ? l + 64 : l;

    // ---- prefetch packed A into regs (latency hidden under x-stage + GEMM1) ----
    u32 abuf[5];
    {
        const u32* Ag = A32 + (size_t)g * AWG;
        #pragma unroll
        for (int j = 0; j < 5; ++j) {
            int p = t + j * 512;
            abuf[j] = (p < AWG) ? Ag[p] : 0u;
        }
    }

    // ---- stage x -> As (expand bf16 to f32; single GEMM path) ----
    if (isf32) {
        const float* xg = (const float*)x + (size_t)g * 8100;
        for (int p = t; p < 8100; p += 512) {
            int r = p / NPG, c = p - r * NPG;
            As[r * SAD + c] = xg[p];
        }
    } else {
        const u32* xg = (const u32*)((const u16*)x + (size_t)g * 8100);
        for (int p = t; p < 4050; p += 512) {
            int r = p / 45, c = (p - r * 45) * 2;
            u32 v = xg[p];
            As[r * SAD + c]     = bflo(v);
            As[r * SAD + c + 1] = bfhi(v);
        }
    }
    __syncthreads();  // B0

    // ---- GEMM1: P = x@W1l, Q = x@W1r + b1 (regs); weights scalar-uniform ----
    float accP[2][8], accQ[2][8];
    {
        const float* bb = wf + WF_B1 + jb;
        #pragma unroll
        for (int j = 0; j < 8; ++j) {
            float bv = bb[j];
            accP[0][j] = 0.f; accP[1][j] = 0.f;
            accQ[0][j] = bv;  accQ[1][j] = bv;
        }
    }
    {
        const float* WL = wf + WF_W1L + jb;
        const float* WR = wf + WF_W1R + jb;
        #pragma unroll 3
        for (int k = 0; k < FIN; ++k) {
            float wl[8], wr[8];
            #pragma unroll
            for (int j = 0; j < 8; ++j) { wl[j] = WL[k * HC + j]; wr[j] = WR[k * HC + j]; }
            float x0 = As[row0 * SAD + k];
            float x1 = As[row1 * SAD + k];
            #pragma unroll
            for (int j = 0; j < 8; ++j) {
                accP[0][j] += x0 * wl[j]; accQ[0][j] += x0 * wr[j];
                accP[1][j] += x1 * wl[j]; accQ[1][j] += x1 * wr[j];
            }
        }
    }
    __syncthreads();  // B1: x reads done, As reusable for A

    // ---- write P to R1; unpack A bytes -> As f32 ----
    *(float4*)(R1 + row0 * SP + jb)     = make_float4(accP[0][0], accP[0][1], accP[0][2], accP[0][3]);
    *(float4*)(R1 + row0 * SP + jb + 4) = make_float4(accP[0][4], accP[0][5], accP[0][6], accP[0][7]);
    if (has2) {
        *(float4*)(R1 + row1 * SP + jb)     = make_float4(accP[1][0], accP[1][1], accP[1][2], accP[1][3]);
        *(float4*)(R1 + row1 * SP + jb + 4) = make_float4(accP[1][4], accP[1][5], accP[1][6], accP[1][7]);
    }
    #pragma unroll
    for (int j = 0; j < 5; ++j) {
        int p = t + j * 512;
        if (p < AWG) {
            int r = p / AW, wc = p - r * AW;
            int c = wc * 4;
            u32 v = abuf[j];
            float* dst = As + r * SAD + c;
            dst[0] = (float)(v & 255u);
            dst[1] = (float)((v >> 8) & 255u);
            dst[2] = (float)((v >> 16) & 255u);       // c+2 <= 90 (pad col ok)
            if (c + 3 < SAD) dst[3] = (float)(v >> 24); // skip: would alias next row
        }
    }
    __syncthreads();  // B2: A complete

    // ---- Agg1: h1 = rc*(A@P) + Q ; rc from A row-sum (free, in-loop) ----
    float r1v[2][8];
    float rc0, rc1;
    {
        float acc[2][8];
        float asum0 = 0.f, asum1 = 0.f;
        #pragma unroll
        for (int i = 0; i < 2; ++i)
            #pragma unroll
            for (int j = 0; j < 8; ++j) acc[i][j] = 0.f;
        for (int k = 0; k < NPG; ++k) {
            float4 p0 = *(const float4*)(R1 + k * SP + jb);     // full-wave broadcast
            float4 p1 = *(const float4*)(R1 + k * SP + jb + 4);
            float pv[8] = {p0.x,p0.y,p0.z,p0.w,p1.x,p1.y,p1.z,p1.w};
            float a0 = As[row0 * SAD + k];
            float a1 = As[row1 * SAD + k];
            asum0 += a0; asum1 += a1;
            #pragma unroll
            for (int j = 0; j < 8; ++j) {
                acc[0][j] += a0 * pv[j];
                acc[1][j] += a1 * pv[j];
            }
        }
        rc0 = 1.0f / fmaxf(asum0, 1.0f);
        rc1 = 1.0f / fmaxf(asum1, 1.0f);
        #pragma unroll
        for (int i = 0; i < 2; ++i) {
            if (i == 0 || has2) {
                int n = i ? row1 : row0;
                float rc = i ? rc1 : rc0;
                float h[8];
                #pragma unroll
                for (int j = 0; j < 8; ++j) h[j] = fmaf(rc, acc[i][j], accQ[i][j]);
                size_t base = 512 + (size_t)(g * NPG + n) * HC + jb;
                if (isf32) {
                    *(float4*)((float*)dout + base)     = make_float4(h[0],h[1],h[2],h[3]);
                    *(float4*)((float*)dout + base + 4) = make_float4(h[4],h[5],h[6],h[7]);
                } else {
                    uint4 pk;
                    pk.x = (u32)f2bf(h[0]) | ((u32)f2bf(h[1]) << 16);
                    pk.y = (u32)f2bf(h[2]) | ((u32)f2bf(h[3]) << 16);
                    pk.z = (u32)f2bf(h[4]) | ((u32)f2bf(h[5]) << 16);
                    pk.w = (u32)f2bf(h[6]) | ((u32)f2bf(h[7]) << 16);
                    *(uint4*)((u16*)dout + base) = pk;
                }
                #pragma unroll
                for (int j = 0; j < 8; ++j) r1v[i][j] = fmaxf(h[j], 0.f);
            }
        }
    }
    __syncthreads();  // B3: P reads done
    #pragma unroll
    for (int j = 0; j < 8; ++j) R1[row0 * SR + jb + j] = r1v[0][j];
    if (has2) {
        #pragma unroll
        for (int j = 0; j < 8; ++j) R1[row1 * SR + jb + j] = r1v[1][j];
    }
    __syncthreads();  // B4

    // ---- GEMM2: P2 = r1@W2l, Q2 = r1@W2r + b2 (regs) ----
    {
        const float* bb = wf + WF_B2 + jb;
        #pragma unroll
        for (int j = 0; j < 8; ++j) {
            float bv = bb[j];
            accP[0][j] = 0.f; accP[1][j] = 0.f;
            accQ[0][j] = bv;  accQ[1][j] = bv;
        }
    }
    {
        const float* WL = wf + WF_W2L + jb;
        const float* WR = wf + WF_W2R + jb;
        #pragma unroll 4
        for (int k = 0; k < HC; ++k) {
            float wl[8], wr[8];
            #pragma unroll
            for (int j = 0; j < 8; ++j) { wl[j] = WL[k * HC + j]; wr[j] = WR[k * HC + j]; }
            float v0 = R1[row0 * SR + k];
            float v1 = R1[row1 * SR + k];
            #pragma unroll
            for (int j = 0; j < 8; ++j) {
                accP[0][j] += v0 * wl[j]; accQ[0][j] += v0 * wr[j];
                accP[1][j] += v1 * wl[j]; accQ[1][j] += v1 * wr[j];
            }
        }
    }
    __syncthreads();  // B5: r1 reads done
    *(float4*)(R1 + row0 * SP + jb)     = make_float4(accP[0][0], accP[0][1], accP[0][2], accP[0][3]);
    *(float4*)(R1 + row0 * SP + jb + 4) = make_float4(accP[0][4], accP[0][5], accP[0][6], accP[0][7]);
    if (has2) {
        *(float4*)(R1 + row1 * SP + jb)     = make_float4(accP[1][0], accP[1][1], accP[1][2], accP[1][3]);
        *(float4*)(R1 + row1 * SP + jb + 4) = make_float4(accP[1][4], accP[1][5], accP[1][6], accP[1][7]);
    }
    __syncthreads();  // B6

    // ---- Agg2: h2 = rc*(A@P2) + Q2 ; key = col 63 ----
    float h2v[2][8];
    {
        float acc[2][8];
        #pragma unroll
        for (int i = 0; i < 2; ++i)
            #pragma unroll
            for (int j = 0; j < 8; ++j) acc[i][j] = 0.f;
        for (int k = 0; k < NPG; ++k) {
            float4 p0 = *(const float4*)(R1 + k * SP + jb);
            float4 p1 = *(const float4*)(R1 + k * SP + jb + 4);
            float pv[8] = {p0.x,p0.y,p0.z,p0.w,p1.x,p1.y,p1.z,p1.w};
            float a0 = As[row0 * SAD + k];
            float a1 = As[row1 * SAD + k];
            #pragma unroll
            for (int j = 0; j < 8; ++j) {
                acc[0][j] += a0 * pv[j];
                acc[1][j] += a1 * pv[j];
            }
        }
        #pragma unroll
        for (int i = 0; i < 2; ++i) {
            if (i == 0 || has2) {
                int n = i ? row1 : row0;
                float rc = i ? rc1 : rc0;
                #pragma unroll
                for (int j = 0; j < 8; ++j)
                    h2v[i][j] = fmaf(rc, acc[i][j], accQ[i][j]);
                if (w == 7) s_key[n] = h2v[i][7];
            }
        }
    }
    __syncthreads();  // B7: P2 reads done; s_key complete
    #pragma unroll
    for (int j = 0; j < 8; ++j) R1[row0 * SR + jb + j] = h2v[0][j];
    if (has2) {
        #pragma unroll
        for (int j = 0; j < 8; ++j) R1[row1 * SR + jb + j] = h2v[1][j];
    }
    // stable descending rank (== stable argsort(-key))
    if (t < NPG) {
        float my = s_key[t];
        int r = 0;
        for (int m2 = 0; m2 < NPG; ++m2) {
            float km = s_key[m2];
            r += (km > my) || (km == my && m2 < t);
        }
        if (r < KP) s_ord[r] = (u16)t;
    }
    __syncthreads();  // B8

    // ---- folded MLP: z = sum p*W_fold + zc ; sigmoid ----
    float zp = 0.f;
    for (int p = t; p < KP * HC; p += 512) {
        int i = p >> 6, c = p & 63;
        int nn = s_ord[i];
        zp += R1[nn * SR + c] * wf[WF_FOLD + p];
    }
    #pragma unroll
    for (int off = 32; off > 0; off >>= 1) zp += __shfl_down(zp, off);
    if ((t & 63) == 0) s_red[t >> 6] = zp;
    __syncthreads();  // B9
    if (t == 0) {
        float z = wf[WF_ZC];
        #pragma unroll
        for (int i = 0; i < 8; ++i) z += s_red[i];
        float sg = 1.0f / (1.0f + expf(-z));
        if (isf32) ((float*)dout)[g] = sg;
        else       ((u16*)dout)[g]   = f2bf(sg);
    }
}

extern "C" void kernel_launch(void* const* d_in, const int* in_sizes, int n_in,
                              void* d_out, int out_size, void* d_ws, size_t ws_size,
                              hipStream_t stream) {
    const void* x   = d_in[0];
    const int*  ei  = (const int*)d_in[1];
    const void* W1l = d_in[3];
    const void* W1r = d_in[4];
    const void* b1  = d_in[5];
    const void* W2l = d_in[6];
    const void* W2r = d_in[7];
    const void* b2  = d_in[8];
    const void* Wl1 = d_in[9];
    const void* bl1 = d_in[10];
    const void* Wl2 = d_in[11];
    const void* bl2 = d_in[12];

    char* ws    = (char*)d_ws;
    u32*  A32   = (u32*)ws;                      // 4,239,360 B (512 x 2070 u32)
    float* wf   = (float*)(ws + 4239360);        // 97,288 B (total ~4.34 MB)

    hipMemsetAsync(A32, 0, 4239360, stream);
    k_pre<<<996, 256, 0, stream>>>((const u32*)x, ei, W1l, W1r, b1, W2l, W2r, b2,
                                   Wl1, bl1, Wl2, bl2, A32, wf);
    k_fused<<<GG, 512, 0, stream>>>(x, A32, wf, d_out);
}